// Round 1
// baseline (529.038 us; speedup 1.0000x reference)
//
#include <hip/hip_runtime.h>
#include <math.h>

#define BB 512
#define LL 10
#define RR 2048
#define DD 256
#define KK 20
#define HH 128
#define NVOCAB 30000
#define GEOD 64

#define NT 512   // threads per fused block (8 waves)

// ---------------- Kernel A: per-vocab-row inverse L2 norm ----------------
__global__ __launch_bounds__(256) void inv_norm_kernel(
    const float* __restrict__ emb, float* __restrict__ invn, int nrows)
{
    int gwave = (blockIdx.x * 256 + threadIdx.x) >> 6;
    int lane  = threadIdx.x & 63;
    if (gwave >= nrows) return;
    const float* row = emb + (size_t)gwave * DD;
    float ssq = 0.f;
    #pragma unroll
    for (int k = 0; k < DD / 64; ++k) {
        float v = row[lane + 64 * k];
        ssq += v * v;
    }
    #pragma unroll
    for (int off = 32; off; off >>= 1) ssq += __shfl_xor(ssq, off);
    if (lane == 0) invn[gwave] = 1.0f / fmaxf(sqrtf(ssq), 1e-12f);
}

// ---------------- Kernel B: fused per-batch pipeline ----------------
__global__ __launch_bounds__(NT) void fused_kernel(
    const int*   __restrict__ text_left,   // [B,L]
    const int*   __restrict__ text_right,  // [B,R]
    const int*   __restrict__ loc_left,    // [B,2]
    const float* __restrict__ distance,    // [B]
    const float* __restrict__ emb,         // [VOCAB,D]
    const float* __restrict__ attn_w,      // [D]
    const float* __restrict__ w_m0, const float* __restrict__ b_m0,  // [K,H],[H]
    const float* __restrict__ w_m1, const float* __restrict__ b_m1,  // [H,H],[H]
    const float* __restrict__ w_m2, const float* __restrict__ b_m2,  // [H,1],[1]
    const float* __restrict__ out_w, const float* __restrict__ out_b,// [1,1],[1]
    const float* __restrict__ lat_tab, const float* __restrict__ lon_tab, // [GEO_V,64]
    const float* __restrict__ w3, const float* __restrict__ b3,      // [D,10],[10]
    const float* __restrict__ w5, const float* __restrict__ b5,      // [64,32],[32]
    const float* __restrict__ w4, const float* __restrict__ b4,      // [164,2],[2]
    const float* __restrict__ invn,        // [VOCAB] precomputed
    float*       __restrict__ out)         // [B]
{
    __shared__ __align__(16) float s_scores[LL][RR];   // 80 KB
    __shared__ __align__(16) float s_q[LL][DD];        // 10 KB (raw emb rows)
    __shared__ float s_invq[LL];
    __shared__ float s_logit[LL];
    __shared__ float s_topk[LL][KK];
    __shared__ float s_h1[LL][HH];                     // 5 KB
    __shared__ float s_h2[LL][HH];                     // 5 KB
    __shared__ float s_h[LL];
    __shared__ float s_x;
    __shared__ float s_feat[164];

    const int b    = blockIdx.x;
    const int tid  = threadIdx.x;
    const int lane = tid & 63;
    const int wid  = tid >> 6;

    // ---- stage 1: gather query rows into LDS (raw values) ----
    for (int t = tid; t < LL * DD; t += NT) {
        int l = t >> 8;        // /256
        int d = t & 255;
        int v = text_left[b * LL + l];
        s_q[l][d] = emb[(size_t)v * DD + d];
    }
    __syncthreads();

    // per-row inv-norm + attention logit (one wave per row)
    for (int l = wid; l < LL; l += (NT / 64)) {
        float ssq = 0.f, dA = 0.f;
        #pragma unroll
        for (int k = 0; k < DD / 64; ++k) {
            float v = s_q[l][lane + 64 * k];
            ssq += v * v;
            dA  += v * attn_w[lane + 64 * k];
        }
        #pragma unroll
        for (int off = 32; off; off >>= 1) {
            ssq += __shfl_xor(ssq, off);
            dA  += __shfl_xor(dA, off);
        }
        if (lane == 0) {
            s_invq[l]  = 1.0f / fmaxf(sqrtf(ssq), 1e-12f);
            s_logit[l] = (text_left[b * LL + l] == 0) ? -INFINITY : dA;
        }
    }
    __syncthreads();

    // ---- stage 2: cosine scores for all (l, r) ----
    for (int k = 0; k < RR / NT; ++k) {
        int r = tid + k * NT;
        int idx = text_right[b * RR + r];
        const float4* erow = (const float4*)(emb + (size_t)idx * DD);
        float inve = invn[idx];
        float acc[LL];
        #pragma unroll
        for (int l = 0; l < LL; ++l) acc[l] = 0.f;
        #pragma unroll
        for (int c = 0; c < 8; ++c) {          // 8 chunks of 128B (one cache line)
            float4 e[8];
            #pragma unroll
            for (int u = 0; u < 8; ++u) e[u] = erow[c * 8 + u];
            #pragma unroll
            for (int l = 0; l < LL; ++l) {
                const float4* q4 = (const float4*)(&s_q[l][0]);
                float a = acc[l];
                #pragma unroll
                for (int u = 0; u < 8; ++u) {
                    float4 qv = q4[c * 8 + u];
                    a += qv.x * e[u].x + qv.y * e[u].y + qv.z * e[u].z + qv.w * e[u].w;
                }
                acc[l] = a;
            }
        }
        #pragma unroll
        for (int l = 0; l < LL; ++l)
            s_scores[l][r] = (acc[l] * s_invq[l]) * inve;
    }
    __syncthreads();

    // ---- stage 3: top-20 (sorted desc) per row via max extraction ----
    {
        volatile float* vsc = (volatile float*)&s_scores[0][0];
        for (int l = wid; l < LL; l += (NT / 64)) {
            volatile float* row = vsc + l * RR;
            for (int it = 0; it < KK; ++it) {
                float bm = -INFINITY;
                int   bi = 0x7fffffff;
                #pragma unroll 4
                for (int j = lane; j < RR; j += 64) {
                    float v = row[j];
                    if (v > bm) { bm = v; bi = j; }
                }
                #pragma unroll
                for (int off = 32; off; off >>= 1) {
                    float ov = __shfl_xor(bm, off);
                    int   oi = __shfl_xor(bi, off);
                    if (ov > bm || (ov == bm && oi < bi)) { bm = ov; bi = oi; }
                }
                if (lane == 0) s_topk[l][it] = bm;
                if ((bi & 63) == lane) row[bi] = -INFINITY;
                __threadfence_block();   // make invalidation visible before next scan
            }
        }
    }
    __syncthreads();

    // ---- stage 4: MLP over topk ----
    for (int t = tid; t < LL * HH; t += NT) {
        int l = t >> 7, c = t & 127;
        float a = b_m0[c];
        #pragma unroll
        for (int k2 = 0; k2 < KK; ++k2) a += s_topk[l][k2] * w_m0[k2 * HH + c];
        s_h1[l][c] = tanhf(a);
    }
    __syncthreads();
    for (int t = tid; t < LL * HH; t += NT) {
        int l = t >> 7, c = t & 127;
        float a = b_m1[c];
        for (int j = 0; j < HH; ++j) a += s_h1[l][j] * w_m1[j * HH + c];
        s_h2[l][c] = tanhf(a);
    }
    __syncthreads();
    for (int l = wid; l < LL; l += (NT / 64)) {
        float a = 0.f;
        #pragma unroll
        for (int k = 0; k < HH / 64; ++k) a += s_h2[l][lane + 64 * k] * w_m2[lane + 64 * k];
        #pragma unroll
        for (int off = 32; off; off >>= 1) a += __shfl_xor(a, off);
        if (lane == 0) s_h[l] = tanhf(a + b_m2[0]);
    }
    __syncthreads();

    // ---- softmax attention + frozen-branch scalar x ----
    if (tid == 0) {
        float mx = -INFINITY;
        #pragma unroll
        for (int l = 0; l < LL; ++l) mx = fmaxf(mx, s_logit[l]);
        float ex[LL];
        float sum = 0.f;
        #pragma unroll
        for (int l = 0; l < LL; ++l) { ex[l] = expf(s_logit[l] - mx); sum += ex[l]; }
        float x = 0.f;
        #pragma unroll
        for (int l = 0; l < LL; ++l) x += s_h[l] * (ex[l] / sum);
        s_x = tanhf(x * out_w[0] + out_b[0]);
    }

    // ---- geo / projection features ----
    for (int t = tid; t < 164; t += NT) {
        float a;
        if (t < 100) {
            int l = t / 10, j = t % 10;
            a = b3[j];
            for (int d = 0; d < DD; ++d) a += s_q[l][d] * w3[d * 10 + j];
        } else if (t < 132) {
            int c = t - 100;
            int v = loc_left[b * 2 + 0];
            a = b5[c];
            for (int d = 0; d < GEOD; ++d) a += lat_tab[v * GEOD + d] * w5[d * 32 + c];
        } else {
            int c = t - 132;
            int v = loc_left[b * 2 + 1];
            a = b5[c];
            for (int d = 0; d < GEOD; ++d) a += lon_tab[v * GEOD + d] * w5[d * 32 + c];
        }
        s_feat[t] = a;
    }
    __syncthreads();

    if (tid == 0) {
        float w0 = b4[0], w1 = b4[1];
        for (int i = 0; i < 164; ++i) {
            w0 += s_feat[i] * w4[i * 2 + 0];
            w1 += s_feat[i] * w4[i * 2 + 1];
        }
        out[b] = w0 * s_x + w1 * distance[b];
    }
}

extern "C" void kernel_launch(void* const* d_in, const int* in_sizes, int n_in,
                              void* d_out, int out_size, void* d_ws, size_t ws_size,
                              hipStream_t stream) {
    const int*   text_left  = (const int*)  d_in[0];
    const int*   text_right = (const int*)  d_in[1];
    const int*   loc_left   = (const int*)  d_in[2];
    const float* distance   = (const float*)d_in[3];
    const float* emb        = (const float*)d_in[4];
    const float* attn_w     = (const float*)d_in[5];
    const float* w_m0       = (const float*)d_in[6];
    const float* b_m0       = (const float*)d_in[7];
    const float* w_m1       = (const float*)d_in[8];
    const float* b_m1       = (const float*)d_in[9];
    const float* w_m2       = (const float*)d_in[10];
    const float* b_m2       = (const float*)d_in[11];
    const float* out_w      = (const float*)d_in[12];
    const float* out_b      = (const float*)d_in[13];
    const float* lat_tab    = (const float*)d_in[14];
    const float* lon_tab    = (const float*)d_in[15];
    const float* w3         = (const float*)d_in[16];
    const float* b3         = (const float*)d_in[17];
    const float* w5         = (const float*)d_in[18];
    const float* b5         = (const float*)d_in[19];
    const float* w4         = (const float*)d_in[20];
    const float* b4         = (const float*)d_in[21];

    float* invn = (float*)d_ws;          // 30000 floats = 120 KB
    float* out  = (float*)d_out;         // [B]

    int nblocksA = (NVOCAB + 3) / 4;     // one wave per row, 4 waves/block
    inv_norm_kernel<<<nblocksA, 256, 0, stream>>>(emb, invn, NVOCAB);

    fused_kernel<<<BB, NT, 0, stream>>>(
        text_left, text_right, loc_left, distance, emb, attn_w,
        w_m0, b_m0, w_m1, b_m1, w_m2, b_m2, out_w, out_b,
        lat_tab, lon_tab, w3, b3, w5, b5, w4, b4, invn, out);
}

// Round 2
// 201.897 us; speedup vs baseline: 2.6203x; 2.6203x over previous
//
#include <hip/hip_runtime.h>
#include <math.h>

#define BB 512
#define LL 10
#define RR 2048
#define DD 256
#define KK 20
#define HH 128
#define NVOCAB 30000
#define GEOD 64

#define NT 1024   // 16 waves

typedef __attribute__((ext_vector_type(8))) short bf16x8;
typedef __attribute__((ext_vector_type(4))) float f32x4;

static __device__ inline unsigned short f2bf(float f) {
    unsigned u = __float_as_uint(f);
    unsigned r = (u + 0x7fff + ((u >> 16) & 1)) >> 16;   // RNE
    return (unsigned short)r;
}

// ---------------- Kernel A: normalized bf16 embedding table ----------------
__global__ __launch_bounds__(256) void normalize_kernel(
    const float* __restrict__ emb, unsigned short* __restrict__ embn)
{
    int row  = blockIdx.x * 4 + (threadIdx.x >> 6);
    int lane = threadIdx.x & 63;
    const float4* r4 = (const float4*)(emb + (size_t)row * DD);
    float4 v = r4[lane];
    float ssq = v.x * v.x + v.y * v.y + v.z * v.z + v.w * v.w;
    #pragma unroll
    for (int off = 32; off; off >>= 1) ssq += __shfl_xor(ssq, off);
    float inv = 1.0f / fmaxf(sqrtf(ssq), 1e-12f);
    ushort4 o;
    o.x = f2bf(v.x * inv); o.y = f2bf(v.y * inv);
    o.z = f2bf(v.z * inv); o.w = f2bf(v.w * inv);
    ((ushort4*)(embn + (size_t)row * DD))[lane] = o;
}

// ---------------- Kernel B: fused per-batch pipeline ----------------
__global__ __launch_bounds__(NT) void fused_kernel(
    const int*   __restrict__ text_left,   // [B,L]
    const int*   __restrict__ text_right,  // [B,R]
    const int*   __restrict__ loc_left,    // [B,2]
    const float* __restrict__ distance,    // [B]
    const float* __restrict__ emb,         // [VOCAB,D] fp32 (raw)
    const float* __restrict__ attn_w,      // [D]
    const float* __restrict__ w_m0, const float* __restrict__ b_m0,
    const float* __restrict__ w_m1, const float* __restrict__ b_m1,
    const float* __restrict__ w_m2, const float* __restrict__ b_m2,
    const float* __restrict__ out_w, const float* __restrict__ out_b,
    const float* __restrict__ lat_tab, const float* __restrict__ lon_tab,
    const float* __restrict__ w3, const float* __restrict__ b3,
    const float* __restrict__ w5, const float* __restrict__ b5,
    const float* __restrict__ w4, const float* __restrict__ b4,
    const unsigned short* __restrict__ embn, // [VOCAB,D] normalized bf16
    float*       __restrict__ out)         // [B]
{
    __shared__ __align__(16) float s_scores[LL][RR];        // 80 KB
    __shared__ __align__(16) float s_q[LL][DD];             // 10 KB raw fp32 q
    __shared__ __align__(16) unsigned short s_qb[16][DD];   // 8 KB normalized bf16 q (rows 10..15 zero)
    __shared__ float s_logit[LL];
    __shared__ float s_topk[LL][KK];
    __shared__ float s_h1[LL][HH];
    __shared__ float s_h2[LL][HH];
    __shared__ float s_h[LL];
    __shared__ float s_x;
    __shared__ float s_feat[164];

    const int b    = blockIdx.x;
    const int tid  = threadIdx.x;
    const int lane = tid & 63;
    const int wid  = tid >> 6;

    // ---- stage raw q rows (fp32, for attn logits + q1 features) ----
    for (int t = tid; t < LL * DD; t += NT) {
        int l = t >> 8, d = t & 255;
        int v = text_left[b * LL + l];
        s_q[l][d] = emb[(size_t)v * DD + d];
    }
    // ---- stage normalized bf16 q rows (A operand), zero-pad rows 10..15 ----
    {
        int t = tid;                 // 16*64 = 1024 == NT, one uint2 (4 bf16) each
        int row = t >> 6, off = (t & 63) * 4;
        uint2 val; val.x = 0u; val.y = 0u;
        if (row < LL) {
            int v = text_left[b * LL + row];
            val = *(const uint2*)(embn + (size_t)v * DD + off);
        }
        *(uint2*)&s_qb[row][off] = val;
    }
    __syncthreads();

    // ---- attention logits (one wave per row) ----
    if (wid < LL) {
        int l = wid;
        float dA = 0.f;
        #pragma unroll
        for (int k = 0; k < DD / 64; ++k)
            dA += s_q[l][lane + 64 * k] * attn_w[lane + 64 * k];
        #pragma unroll
        for (int off = 32; off; off >>= 1) dA += __shfl_xor(dA, off);
        if (lane == 0)
            s_logit[l] = (text_left[b * LL + l] == 0) ? -INFINITY : dA;
    }

    // ---- MFMA GEMM: scores[16][2048] = Qn[16][256] x Dn[2048][256]^T ----
    {
        // A fragments: lane holds A[m=lane&15][k=(lane>>4)*8 + kk*32 .. +7]
        bf16x8 afrag[8];
        const unsigned short* qb = &s_qb[lane & 15][0];
        const int ko = (lane >> 4) * 8;
        #pragma unroll
        for (int kk = 0; kk < 8; ++kk)
            afrag[kk] = *(const bf16x8*)(qb + kk * 32 + ko);

        const int* trb = text_right + b * RR;
        for (int nt = wid; nt < RR / 16; nt += NT / 64) {
            int n0 = nt * 16;
            int doc = trb[n0 + (lane & 15)];
            const unsigned short* bp = embn + (size_t)doc * DD + ko;
            f32x4 acc = {0.f, 0.f, 0.f, 0.f};
            #pragma unroll
            for (int kk = 0; kk < 8; ++kk) {
                bf16x8 bfrag = *(const bf16x8*)(bp + kk * 32);
                acc = __builtin_amdgcn_mfma_f32_16x16x32_bf16(afrag[kk], bfrag, acc, 0, 0, 0);
            }
            // C: col = lane&15, row m = (lane>>4)*4 + v
            #pragma unroll
            for (int v = 0; v < 4; ++v) {
                int m = (lane >> 4) * 4 + v;
                if (m < LL) s_scores[m][n0 + (lane & 15)] = acc[v];
            }
        }
    }
    __syncthreads();

    // ---- top-20 (sorted desc) per row via max extraction ----
    if (wid < LL) {
        int l = wid;
        volatile float* row = (volatile float*)&s_scores[l][0];
        for (int it = 0; it < KK; ++it) {
            float bm = -INFINITY;
            int   bi = 0x7fffffff;
            #pragma unroll 4
            for (int j = lane; j < RR; j += 64) {
                float v = row[j];
                if (v > bm) { bm = v; bi = j; }
            }
            #pragma unroll
            for (int off = 32; off; off >>= 1) {
                float ov = __shfl_xor(bm, off);
                int   oi = __shfl_xor(bi, off);
                if (ov > bm || (ov == bm && oi < bi)) { bm = ov; bi = oi; }
            }
            if (lane == 0) s_topk[l][it] = bm;
            if ((bi & 63) == lane) row[bi] = -INFINITY;
            __threadfence_block();
        }
    }
    __syncthreads();

    // ---- MLP over topk ----
    for (int t = tid; t < LL * HH; t += NT) {
        int l = t >> 7, c = t & 127;
        float a = b_m0[c];
        #pragma unroll
        for (int k2 = 0; k2 < KK; ++k2) a += s_topk[l][k2] * w_m0[k2 * HH + c];
        s_h1[l][c] = tanhf(a);
    }
    __syncthreads();
    for (int t = tid; t < LL * HH; t += NT) {
        int l = t >> 7, c = t & 127;
        float a = b_m1[c];
        for (int j = 0; j < HH; ++j) a += s_h1[l][j] * w_m1[j * HH + c];
        s_h2[l][c] = tanhf(a);
    }
    __syncthreads();
    if (wid < LL) {
        int l = wid;
        float a = 0.f;
        #pragma unroll
        for (int k = 0; k < HH / 64; ++k) a += s_h2[l][lane + 64 * k] * w_m2[lane + 64 * k];
        #pragma unroll
        for (int off = 32; off; off >>= 1) a += __shfl_xor(a, off);
        if (lane == 0) s_h[l] = tanhf(a + b_m2[0]);
    }
    __syncthreads();

    // ---- softmax attention + frozen-branch scalar x ----
    if (tid == 0) {
        float mx = -INFINITY;
        #pragma unroll
        for (int l = 0; l < LL; ++l) mx = fmaxf(mx, s_logit[l]);
        float ex[LL];
        float sum = 0.f;
        #pragma unroll
        for (int l = 0; l < LL; ++l) { ex[l] = expf(s_logit[l] - mx); sum += ex[l]; }
        float x = 0.f;
        #pragma unroll
        for (int l = 0; l < LL; ++l) x += s_h[l] * (ex[l] / sum);
        s_x = tanhf(x * out_w[0] + out_b[0]);
    }

    // ---- geo / projection features ----
    for (int t = tid; t < 164; t += NT) {
        float a;
        if (t < 100) {
            int l = t / 10, j = t % 10;
            a = b3[j];
            for (int d = 0; d < DD; ++d) a += s_q[l][d] * w3[d * 10 + j];
        } else if (t < 132) {
            int c = t - 100;
            int v = loc_left[b * 2 + 0];
            a = b5[c];
            for (int d = 0; d < GEOD; ++d) a += lat_tab[v * GEOD + d] * w5[d * 32 + c];
        } else {
            int c = t - 132;
            int v = loc_left[b * 2 + 1];
            a = b5[c];
            for (int d = 0; d < GEOD; ++d) a += lon_tab[v * GEOD + d] * w5[d * 32 + c];
        }
        s_feat[t] = a;
    }
    __syncthreads();

    if (tid == 0) {
        float w0 = b4[0], w1 = b4[1];
        for (int i = 0; i < 164; ++i) {
            w0 += s_feat[i] * w4[i * 2 + 0];
            w1 += s_feat[i] * w4[i * 2 + 1];
        }
        out[b] = w0 * s_x + w1 * distance[b];
    }
}

extern "C" void kernel_launch(void* const* d_in, const int* in_sizes, int n_in,
                              void* d_out, int out_size, void* d_ws, size_t ws_size,
                              hipStream_t stream) {
    const int*   text_left  = (const int*)  d_in[0];
    const int*   text_right = (const int*)  d_in[1];
    const int*   loc_left   = (const int*)  d_in[2];
    const float* distance   = (const float*)d_in[3];
    const float* emb        = (const float*)d_in[4];
    const float* attn_w     = (const float*)d_in[5];
    const float* w_m0       = (const float*)d_in[6];
    const float* b_m0       = (const float*)d_in[7];
    const float* w_m1       = (const float*)d_in[8];
    const float* b_m1       = (const float*)d_in[9];
    const float* w_m2       = (const float*)d_in[10];
    const float* b_m2       = (const float*)d_in[11];
    const float* out_w      = (const float*)d_in[12];
    const float* out_b      = (const float*)d_in[13];
    const float* lat_tab    = (const float*)d_in[14];
    const float* lon_tab    = (const float*)d_in[15];
    const float* w3         = (const float*)d_in[16];
    const float* b3         = (const float*)d_in[17];
    const float* w5         = (const float*)d_in[18];
    const float* b5         = (const float*)d_in[19];
    const float* w4         = (const float*)d_in[20];
    const float* b4         = (const float*)d_in[21];

    unsigned short* embn = (unsigned short*)d_ws;   // 30000*256 bf16 = 15.36 MB
    float* out = (float*)d_out;

    normalize_kernel<<<NVOCAB / 4, 256, 0, stream>>>(emb, embn);

    fused_kernel<<<BB, NT, 0, stream>>>(
        text_left, text_right, loc_left, distance, emb, attn_w,
        w_m0, b_m0, w_m1, b_m1, w_m2, b_m2, out_w, out_b,
        lat_tab, lon_tab, w3, b3, w5, b5, w4, b4, embn, out);
}

// Round 3
// 180.924 us; speedup vs baseline: 2.9241x; 1.1159x over previous
//
#include <hip/hip_runtime.h>
#include <hip/hip_fp16.h>
#include <math.h>

#define BB 512
#define LL 10
#define RR 2048
#define DD 256
#define KK 20
#define HH 128
#define NVOCAB 30000
#define GEOD 64

#define NT 1024          // 16 waves
#define RP (RR + 4)      // key row pad: stride 2052 u16 -> quarter-waves 8 banks apart

typedef __attribute__((ext_vector_type(8))) short bf16x8;
typedef __attribute__((ext_vector_type(4))) float f32x4;

static __device__ inline unsigned short f2bf(float f) {
    unsigned u = __float_as_uint(f);
    unsigned r = (u + 0x7fff + ((u >> 16) & 1)) >> 16;   // RNE
    return (unsigned short)r;
}

// ---------------- Kernel A: normalized bf16 embedding table ----------------
__global__ __launch_bounds__(256) void normalize_kernel(
    const float* __restrict__ emb, unsigned short* __restrict__ embn)
{
    int row  = blockIdx.x * 4 + (threadIdx.x >> 6);
    int lane = threadIdx.x & 63;
    const float4* r4 = (const float4*)(emb + (size_t)row * DD);
    float4 v = r4[lane];
    float ssq = v.x * v.x + v.y * v.y + v.z * v.z + v.w * v.w;
    #pragma unroll
    for (int off = 32; off; off >>= 1) ssq += __shfl_xor(ssq, off);
    float inv = 1.0f / fmaxf(sqrtf(ssq), 1e-12f);
    ushort4 o;
    o.x = f2bf(v.x * inv); o.y = f2bf(v.y * inv);
    o.z = f2bf(v.z * inv); o.w = f2bf(v.w * inv);
    ((ushort4*)(embn + (size_t)row * DD))[lane] = o;
}

// wave-wide max of u32 via DPP (VALU pipe), broadcast from lane 63
static __device__ inline unsigned wave_umax_u32(unsigned x)
{
    unsigned t;
    t = (unsigned)__builtin_amdgcn_update_dpp((int)x, (int)x, 0x111, 0xF, 0xF, false); x = x > t ? x : t; // row_shr:1
    t = (unsigned)__builtin_amdgcn_update_dpp((int)x, (int)x, 0x112, 0xF, 0xF, false); x = x > t ? x : t; // row_shr:2
    t = (unsigned)__builtin_amdgcn_update_dpp((int)x, (int)x, 0x114, 0xF, 0xF, false); x = x > t ? x : t; // row_shr:4
    t = (unsigned)__builtin_amdgcn_update_dpp((int)x, (int)x, 0x118, 0xF, 0xF, false); x = x > t ? x : t; // row_shr:8
    t = (unsigned)__builtin_amdgcn_update_dpp((int)x, (int)x, 0x142, 0xF, 0xF, false); x = x > t ? x : t; // row_bcast:15
    t = (unsigned)__builtin_amdgcn_update_dpp((int)x, (int)x, 0x143, 0xF, 0xF, false); x = x > t ? x : t; // row_bcast:31
    return (unsigned)__builtin_amdgcn_readlane((int)x, 63);
}

// per-lane top-2 packed keys over its 32 strided slots, skipping extracted ones
static __device__ inline void build_top2(const unsigned short* __restrict__ row,
                                         int lane, unsigned extmask,
                                         unsigned& k1, unsigned& k2)
{
    unsigned m1 = 0u, m2 = 0u;
    #pragma unroll
    for (int k = 0; k < 32; ++k) {
        int j = lane + 64 * k;
        unsigned key = ((unsigned)row[j] << 16) | (unsigned)(2047 - j);
        key = ((extmask >> k) & 1u) ? 0u : key;
        bool gt = key > m1;
        unsigned nm2 = (key > m2) ? key : m2;
        m2 = gt ? m1 : nm2;
        m1 = gt ? key : m1;
    }
    k1 = m1; k2 = m2;
}

// ---------------- Kernel B: fused per-batch pipeline ----------------
__global__ __launch_bounds__(NT, 8) void fused_kernel(
    const int*   __restrict__ text_left,
    const int*   __restrict__ text_right,
    const int*   __restrict__ loc_left,
    const float* __restrict__ distance,
    const float* __restrict__ emb,
    const float* __restrict__ attn_w,
    const float* __restrict__ w_m0, const float* __restrict__ b_m0,
    const float* __restrict__ w_m1, const float* __restrict__ b_m1,
    const float* __restrict__ w_m2, const float* __restrict__ b_m2,
    const float* __restrict__ out_w, const float* __restrict__ out_b,
    const float* __restrict__ lat_tab, const float* __restrict__ lon_tab,
    const float* __restrict__ w3, const float* __restrict__ b3,
    const float* __restrict__ w5, const float* __restrict__ b5,
    const float* __restrict__ w4, const float* __restrict__ b4,
    const unsigned short* __restrict__ embn,
    float*       __restrict__ out)
{
    __shared__ __align__(16) unsigned short s_keys[LL][RP];   // ~41 KB orderable fp16 keys
    __shared__ __align__(16) float s_q[LL][DD];               // 10 KB raw fp32 q
    __shared__ __align__(16) unsigned short s_qb[16][DD];     // 8 KB bf16 q, 16B-chunk XOR swizzle
    __shared__ float s_logit[LL];
    __shared__ float s_topk[LL][KK];
    __shared__ float s_h1[LL][HH];
    __shared__ float s_h2[LL][HH];
    __shared__ float s_h[LL];
    __shared__ float s_x;
    __shared__ float s_feat[164];

    const int b    = blockIdx.x;
    const int tid  = threadIdx.x;
    const int lane = tid & 63;
    const int wid  = tid >> 6;

    // ---- phase A: stage q rows ----
    for (int t = tid; t < LL * DD; t += NT) {
        int l = t >> 8, d = t & 255;
        int v = text_left[b * LL + l];
        s_q[l][d] = emb[(size_t)v * DD + d];
    }
    {   // bf16 normalized q rows, swizzled: chunk c of row r stored at c ^ (r&7)
        int r = tid >> 6, h = tid & 63;
        int c = h >> 1, half = h & 1;
        uint2 val; val.x = 0u; val.y = 0u;
        if (r < LL) {
            int v = text_left[b * LL + r];
            val = *(const uint2*)(embn + (size_t)v * DD + h * 4);
        }
        *(uint2*)(&s_qb[0][0] + r * DD + ((c ^ (r & 7)) << 3) + (half << 2)) = val;
    }
    __syncthreads();

    // ---- phase B: MFMA GEMM, write orderable-fp16 keys ----
    {
        bf16x8 afrag[8];
        const int m15 = lane & 15, q = lane >> 4;
        #pragma unroll
        for (int kk = 0; kk < 8; ++kk)
            afrag[kk] = *(const bf16x8*)(&s_qb[0][0] + m15 * DD + (((kk * 4 + q) ^ (m15 & 7)) << 3));

        const int* trb = text_right + b * RR;
        #pragma unroll 1
        for (int nt = wid; nt < RR / 16; nt += NT / 64) {
            int n0 = nt * 16;
            int doc = trb[n0 + m15];
            const unsigned short* bp = embn + (size_t)doc * DD + q * 8;
            f32x4 acc = {0.f, 0.f, 0.f, 0.f};
            #pragma unroll 4
            for (int kk = 0; kk < 8; ++kk) {
                bf16x8 bfrag = *(const bf16x8*)(bp + kk * 32);
                acc = __builtin_amdgcn_mfma_f32_16x16x32_bf16(afrag[kk], bfrag, acc, 0, 0, 0);
            }
            #pragma unroll
            for (int v = 0; v < 4; ++v) {
                int m = q * 4 + v;
                unsigned hb = (unsigned)__half_as_ushort(__float2half(acc[v]));
                unsigned okey = hb ^ ((hb & 0x8000u) ? 0xFFFFu : 0x8000u);
                if (m < LL) s_keys[m][n0 + m15] = (unsigned short)okey;
            }
        }
    }
    __syncthreads();

    // ---- phase C: waves 0-9 top-k; waves 10-15 logits + geo features ----
    if (wid < LL) {
        const int l = wid;
        const unsigned short* krow = &s_keys[l][0];
        unsigned extmask = 0u, k1, k2;
        build_top2(krow, lane, extmask, k1, k2);
        #pragma unroll 1
        for (int it = 0; it < KK; ++it) {
            unsigned bmk = wave_umax_u32(k1);
            if (k1 == bmk) {                      // unique owner (keys unique)
                unsigned o16 = bmk >> 16;
                unsigned hb = (o16 & 0x8000u) ? (o16 & 0x7FFFu) : (o16 ^ 0xFFFFu);
                s_topk[l][it] = __half2float(__ushort_as_half((unsigned short)hb));
                int j = 2047 - (int)(bmk & 0xFFFFu);
                extmask |= 1u << (j >> 6);
                k1 = k2; k2 = 0u;
            }
            if (__any(k1 == 0u)) {               // rare refill
                if (k1 == 0u) build_top2(krow, lane, extmask, k1, k2);
            }
        }
    } else {
        // attention logits (rows striped over waves 10..15)
        for (int l = wid - 10; l < LL; l += 6) {
            float dA = 0.f;
            #pragma unroll
            for (int k = 0; k < DD / 64; ++k)
                dA += s_q[l][lane + 64 * k] * attn_w[lane + 64 * k];
            #pragma unroll
            for (int off = 32; off; off >>= 1) dA += __shfl_xor(dA, off);
            if (lane == 0)
                s_logit[l] = (text_left[b * LL + l] == 0) ? -INFINITY : dA;
        }
        // geo / projection features
        for (int t = (wid - 10) * 64 + lane; t < 164; t += 384) {
            float a;
            if (t < 100) {
                int l = t / 10, j = t % 10;
                a = b3[j];
                for (int d = 0; d < DD; ++d) a += s_q[l][d] * w3[d * 10 + j];
            } else if (t < 132) {
                int c = t - 100;
                int v = loc_left[b * 2 + 0];
                a = b5[c];
                for (int d = 0; d < GEOD; ++d) a += lat_tab[v * GEOD + d] * w5[d * 32 + c];
            } else {
                int c = t - 132;
                int v = loc_left[b * 2 + 1];
                a = b5[c];
                for (int d = 0; d < GEOD; ++d) a += lon_tab[v * GEOD + d] * w5[d * 32 + c];
            }
            s_feat[t] = a;
        }
    }
    __syncthreads();

    // ---- phase D: MLP over topk ----
    for (int t = tid; t < LL * HH; t += NT) {
        int l = t >> 7, c = t & 127;
        float a = b_m0[c];
        #pragma unroll
        for (int k2 = 0; k2 < KK; ++k2) a += s_topk[l][k2] * w_m0[k2 * HH + c];
        s_h1[l][c] = tanhf(a);
    }
    __syncthreads();
    for (int t = tid; t < LL * HH; t += NT) {
        int l = t >> 7, c = t & 127;
        float a = b_m1[c];
        for (int j = 0; j < HH; ++j) a += s_h1[l][j] * w_m1[j * HH + c];
        s_h2[l][c] = tanhf(a);
    }
    __syncthreads();
    if (wid < LL) {
        int l = wid;
        float a = 0.f;
        #pragma unroll
        for (int k = 0; k < HH / 64; ++k) a += s_h2[l][lane + 64 * k] * w_m2[lane + 64 * k];
        #pragma unroll
        for (int off = 32; off; off >>= 1) a += __shfl_xor(a, off);
        if (lane == 0) s_h[l] = tanhf(a + b_m2[0]);
    }
    __syncthreads();

    if (tid == 0) {
        float mx = -INFINITY;
        #pragma unroll
        for (int l = 0; l < LL; ++l) mx = fmaxf(mx, s_logit[l]);
        float ex[LL];
        float sum = 0.f;
        #pragma unroll
        for (int l = 0; l < LL; ++l) { ex[l] = expf(s_logit[l] - mx); sum += ex[l]; }
        float x = 0.f;
        #pragma unroll
        for (int l = 0; l < LL; ++l) x += s_h[l] * (ex[l] / sum);
        float xo = tanhf(x * out_w[0] + out_b[0]);

        float w0 = b4[0], w1 = b4[1];
        for (int i = 0; i < 164; ++i) {
            w0 += s_feat[i] * w4[i * 2 + 0];
            w1 += s_feat[i] * w4[i * 2 + 1];
        }
        out[b] = w0 * xo + w1 * distance[b];
    }
}

extern "C" void kernel_launch(void* const* d_in, const int* in_sizes, int n_in,
                              void* d_out, int out_size, void* d_ws, size_t ws_size,
                              hipStream_t stream) {
    const int*   text_left  = (const int*)  d_in[0];
    const int*   text_right = (const int*)  d_in[1];
    const int*   loc_left   = (const int*)  d_in[2];
    const float* distance   = (const float*)d_in[3];
    const float* emb        = (const float*)d_in[4];
    const float* attn_w     = (const float*)d_in[5];
    const float* w_m0       = (const float*)d_in[6];
    const float* b_m0       = (const float*)d_in[7];
    const float* w_m1       = (const float*)d_in[8];
    const float* b_m1       = (const float*)d_in[9];
    const float* w_m2       = (const float*)d_in[10];
    const float* b_m2       = (const float*)d_in[11];
    const float* out_w      = (const float*)d_in[12];
    const float* out_b      = (const float*)d_in[13];
    const float* lat_tab    = (const float*)d_in[14];
    const float* lon_tab    = (const float*)d_in[15];
    const float* w3         = (const float*)d_in[16];
    const float* b3         = (const float*)d_in[17];
    const float* w5         = (const float*)d_in[18];
    const float* b5         = (const float*)d_in[19];
    const float* w4         = (const float*)d_in[20];
    const float* b4         = (const float*)d_in[21];

    unsigned short* embn = (unsigned short*)d_ws;   // 15.36 MB
    float* out = (float*)d_out;

    normalize_kernel<<<NVOCAB / 4, 256, 0, stream>>>(emb, embn);

    fused_kernel<<<BB, NT, 0, stream>>>(
        text_left, text_right, loc_left, distance, emb, attn_w,
        w_m0, b_m0, w_m1, b_m1, w_m2, b_m2, out_w, out_b,
        lat_tab, lon_tab, w3, b3, w5, b5, w4, b4, embn, out);
}

// Round 4
// 97.562 us; speedup vs baseline: 5.4226x; 1.8545x over previous
//
#include <hip/hip_runtime.h>
#include <hip/hip_fp16.h>
#include <math.h>

#define BB 512
#define LL 10
#define RR 2048
#define DD 256
#define KK 20
#define HH 128
#define NVOCAB 30000
#define GEOD 64

#define NT 1024          // 16 waves
#define RP (RR + 4)      // key row pad: stride 2052 u16

#define FP8_SCALE   64.0f
#define FP8_DESCALE (1.0f / 4096.0f)   // 1/(64*64)

typedef __attribute__((ext_vector_type(4))) float f32x4;

// ---------------- Kernel A: normalized fp8(e4m3) embedding table ----------------
__global__ __launch_bounds__(256) void normalize_kernel(
    const float* __restrict__ emb, unsigned char* __restrict__ emb8)
{
    int row  = blockIdx.x * 4 + (threadIdx.x >> 6);
    int lane = threadIdx.x & 63;
    const float4* r4 = (const float4*)(emb + (size_t)row * DD);
    float4 v = r4[lane];
    float ssq = v.x * v.x + v.y * v.y + v.z * v.z + v.w * v.w;
    #pragma unroll
    for (int off = 32; off; off >>= 1) ssq += __shfl_xor(ssq, off);
    float s = FP8_SCALE / fmaxf(sqrtf(ssq), 1e-12f);
    unsigned pk = 0;
    pk = (unsigned)__builtin_amdgcn_cvt_pk_fp8_f32(v.x * s, v.y * s, (int)pk, false);
    pk = (unsigned)__builtin_amdgcn_cvt_pk_fp8_f32(v.z * s, v.w * s, (int)pk, true);
    ((unsigned*)(emb8 + (size_t)row * DD))[lane] = pk;
}

// wave-wide max of u32 via DPP, broadcast from lane 63
static __device__ inline unsigned wave_umax_u32(unsigned x)
{
    unsigned t;
    t = (unsigned)__builtin_amdgcn_update_dpp((int)x, (int)x, 0x111, 0xF, 0xF, false); x = x > t ? x : t;
    t = (unsigned)__builtin_amdgcn_update_dpp((int)x, (int)x, 0x112, 0xF, 0xF, false); x = x > t ? x : t;
    t = (unsigned)__builtin_amdgcn_update_dpp((int)x, (int)x, 0x114, 0xF, 0xF, false); x = x > t ? x : t;
    t = (unsigned)__builtin_amdgcn_update_dpp((int)x, (int)x, 0x118, 0xF, 0xF, false); x = x > t ? x : t;
    t = (unsigned)__builtin_amdgcn_update_dpp((int)x, (int)x, 0x142, 0xF, 0xF, false); x = x > t ? x : t;
    t = (unsigned)__builtin_amdgcn_update_dpp((int)x, (int)x, 0x143, 0xF, 0xF, false); x = x > t ? x : t;
    return (unsigned)__builtin_amdgcn_readlane((int)x, 63);
}

// per-lane top-2 packed keys over its 32 strided slots, skipping extracted ones
static __device__ inline void build_top2(const unsigned short* __restrict__ row,
                                         int lane, unsigned extmask,
                                         unsigned& k1, unsigned& k2)
{
    unsigned m1 = 0u, m2 = 0u;
    #pragma unroll
    for (int k = 0; k < 32; ++k) {
        int j = lane + 64 * k;
        unsigned key = ((unsigned)row[j] << 16) | (unsigned)(2047 - j);
        key = ((extmask >> k) & 1u) ? 0u : key;
        bool gt = key > m1;
        unsigned nm2 = (key > m2) ? key : m2;
        m2 = gt ? m1 : nm2;
        m1 = gt ? key : m1;
    }
    k1 = m1; k2 = m2;
}

// ---------------- Kernel B: fused per-batch pipeline ----------------
__global__ __launch_bounds__(NT, 8) void fused_kernel(
    const int*   __restrict__ text_left,
    const int*   __restrict__ text_right,
    const int*   __restrict__ loc_left,
    const float* __restrict__ distance,
    const float* __restrict__ emb,
    const float* __restrict__ attn_w,
    const float* __restrict__ w_m0, const float* __restrict__ b_m0,
    const float* __restrict__ w_m1, const float* __restrict__ b_m1,
    const float* __restrict__ w_m2, const float* __restrict__ b_m2,
    const float* __restrict__ out_w, const float* __restrict__ out_b,
    const float* __restrict__ lat_tab, const float* __restrict__ lon_tab,
    const float* __restrict__ w3, const float* __restrict__ b3,
    const float* __restrict__ w5, const float* __restrict__ b5,
    const float* __restrict__ w4, const float* __restrict__ b4,
    const unsigned char* __restrict__ emb8,   // [VOCAB,D] normalized e4m3 (x64)
    float*       __restrict__ out)
{
    __shared__ __align__(16) unsigned short s_keys[LL][RP];   // ~41 KB orderable fp16 keys
    __shared__ __align__(16) float s_q[LL][DD];               // 10 KB raw fp32 q
    __shared__ __align__(16) unsigned char s_qa[16][DD];      // 4 KB fp8 q, 8B-chunk XOR swizzle
    __shared__ float s_logit[LL];
    __shared__ float s_topk[LL][KK];
    __shared__ float s_h1[LL][HH];
    __shared__ float s_h2[LL][HH];
    __shared__ float s_h[LL];
    __shared__ float s_feat[164];

    const int b    = blockIdx.x;
    const int tid  = threadIdx.x;
    const int lane = tid & 63;
    const int wid  = tid >> 6;

    // ---- phase A: stage q rows ----
    for (int t = tid; t < LL * DD; t += NT) {
        int l = t >> 8, d = t & 255;
        int v = text_left[b * LL + l];
        s_q[l][d] = emb[(size_t)v * DD + d];
    }
    {   // fp8 q rows, swizzled: 8B chunk c of row r stored at c ^ (r&7)
        int r = tid >> 6, h = tid & 63;      // h: 4B chunk within row
        int c = h >> 1, half = h & 1;
        unsigned val = 0u;
        if (r < LL) {
            int v = text_left[b * LL + r];
            val = *(const unsigned*)(emb8 + (size_t)v * DD + h * 4);
        }
        *(unsigned*)(&s_qa[0][0] + r * DD + (((c ^ (r & 7)) << 3) + (half << 2))) = val;
    }
    __syncthreads();

    // ---- phase B: fp8 MFMA GEMM, write orderable-fp16 keys ----
    {
        const int m15 = lane & 15, q = lane >> 4;
        long long afrag[8];
        #pragma unroll
        for (int kk = 0; kk < 8; ++kk)
            afrag[kk] = *(const long long*)(&s_qa[0][0] + m15 * DD + (((kk * 4 + q) ^ (m15 & 7)) << 3));

        const int* trb = text_right + b * RR;
        int docs[8];
        #pragma unroll
        for (int i = 0; i < 8; ++i)
            docs[i] = trb[(wid + i * 16) * 16 + m15];

        #pragma unroll 1
        for (int i = 0; i < 8; ++i) {
            int n0 = (wid + i * 16) * 16;
            const unsigned char* bp = emb8 + (size_t)docs[i] * DD + q * 8;
            f32x4 acc = {0.f, 0.f, 0.f, 0.f};
            #pragma unroll
            for (int kk = 0; kk < 8; ++kk) {
                long long bfrag = *(const long long*)(bp + kk * 32);
                acc = __builtin_amdgcn_mfma_f32_16x16x32_fp8_fp8(afrag[kk], bfrag, acc, 0, 0, 0);
            }
            #pragma unroll
            for (int v = 0; v < 4; ++v) {
                int m = q * 4 + v;
                float sc = acc[v] * FP8_DESCALE;
                unsigned hb = (unsigned)__half_as_ushort(__float2half(sc));
                unsigned okey = hb ^ ((hb & 0x8000u) ? 0xFFFFu : 0x8000u);
                if (m < LL) s_keys[m][n0 + m15] = (unsigned short)okey;
            }
        }
    }
    __syncthreads();

    // ---- phase C: waves 0-9 top-k; waves 10-15 logits + geo features ----
    if (wid < LL) {
        const int l = wid;
        const unsigned short* krow = &s_keys[l][0];
        unsigned extmask = 0u, k1, k2;
        build_top2(krow, lane, extmask, k1, k2);
        #pragma unroll 1
        for (int it = 0; it < KK; ++it) {
            unsigned bmk = wave_umax_u32(k1);
            if (k1 == bmk) {
                unsigned o16 = bmk >> 16;
                unsigned hb = (o16 & 0x8000u) ? (o16 & 0x7FFFu) : (o16 ^ 0xFFFFu);
                s_topk[l][it] = __half2float(__ushort_as_half((unsigned short)hb));
                int j = 2047 - (int)(bmk & 0xFFFFu);
                extmask |= 1u << (j >> 6);
                k1 = k2; k2 = 0u;
            }
            if (__any(k1 == 0u)) {
                if (k1 == 0u) build_top2(krow, lane, extmask, k1, k2);
            }
        }
    } else {
        for (int l = wid - 10; l < LL; l += 6) {
            float dA = 0.f;
            #pragma unroll
            for (int k = 0; k < DD / 64; ++k)
                dA += s_q[l][lane + 64 * k] * attn_w[lane + 64 * k];
            #pragma unroll
            for (int off = 32; off; off >>= 1) dA += __shfl_xor(dA, off);
            if (lane == 0)
                s_logit[l] = (text_left[b * LL + l] == 0) ? -INFINITY : dA;
        }
        for (int t = (wid - 10) * 64 + lane; t < 164; t += 384) {
            float a;
            if (t < 100) {
                int l = t / 10, j = t % 10;
                a = b3[j];
                for (int d = 0; d < DD; ++d) a += s_q[l][d] * w3[d * 10 + j];
            } else if (t < 132) {
                int c = t - 100;
                int v = loc_left[b * 2 + 0];
                a = b5[c];
                for (int d = 0; d < GEOD; ++d) a += lat_tab[v * GEOD + d] * w5[d * 32 + c];
            } else {
                int c = t - 132;
                int v = loc_left[b * 2 + 1];
                a = b5[c];
                for (int d = 0; d < GEOD; ++d) a += lon_tab[v * GEOD + d] * w5[d * 32 + c];
            }
            s_feat[t] = a;
        }
    }
    __syncthreads();

    // ---- phase D: MLP over topk ----
    for (int t = tid; t < LL * HH; t += NT) {
        int l = t >> 7, c = t & 127;
        float a = b_m0[c];
        #pragma unroll
        for (int k2 = 0; k2 < KK; ++k2) a += s_topk[l][k2] * w_m0[k2 * HH + c];
        s_h1[l][c] = tanhf(a);
    }
    __syncthreads();
    for (int t = tid; t < LL * HH; t += NT) {
        int l = t >> 7, c = t & 127;
        float a = b_m1[c];
        for (int j = 0; j < HH; ++j) a += s_h1[l][j] * w_m1[j * HH + c];
        s_h2[l][c] = tanhf(a);
    }
    __syncthreads();
    if (wid < LL) {
        int l = wid;
        float a = 0.f;
        #pragma unroll
        for (int k = 0; k < HH / 64; ++k) a += s_h2[l][lane + 64 * k] * w_m2[lane + 64 * k];
        #pragma unroll
        for (int off = 32; off; off >>= 1) a += __shfl_xor(a, off);
        if (lane == 0) s_h[l] = tanhf(a + b_m2[0]);
    }
    __syncthreads();

    if (tid == 0) {
        float mx = -INFINITY;
        #pragma unroll
        for (int l = 0; l < LL; ++l) mx = fmaxf(mx, s_logit[l]);
        float ex[LL];
        float sum = 0.f;
        #pragma unroll
        for (int l = 0; l < LL; ++l) { ex[l] = expf(s_logit[l] - mx); sum += ex[l]; }
        float x = 0.f;
        #pragma unroll
        for (int l = 0; l < LL; ++l) x += s_h[l] * (ex[l] / sum);
        float xo = tanhf(x * out_w[0] + out_b[0]);

        float w0 = b4[0], w1 = b4[1];
        for (int i = 0; i < 164; ++i) {
            w0 += s_feat[i] * w4[i * 2 + 0];
            w1 += s_feat[i] * w4[i * 2 + 1];
        }
        out[b] = w0 * xo + w1 * distance[b];
    }
}

extern "C" void kernel_launch(void* const* d_in, const int* in_sizes, int n_in,
                              void* d_out, int out_size, void* d_ws, size_t ws_size,
                              hipStream_t stream) {
    const int*   text_left  = (const int*)  d_in[0];
    const int*   text_right = (const int*)  d_in[1];
    const int*   loc_left   = (const int*)  d_in[2];
    const float* distance   = (const float*)d_in[3];
    const float* emb        = (const float*)d_in[4];
    const float* attn_w     = (const float*)d_in[5];
    const float* w_m0       = (const float*)d_in[6];
    const float* b_m0       = (const float*)d_in[7];
    const float* w_m1       = (const float*)d_in[8];
    const float* b_m1       = (const float*)d_in[9];
    const float* w_m2       = (const float*)d_in[10];
    const float* b_m2       = (const float*)d_in[11];
    const float* out_w      = (const float*)d_in[12];
    const float* out_b      = (const float*)d_in[13];
    const float* lat_tab    = (const float*)d_in[14];
    const float* lon_tab    = (const float*)d_in[15];
    const float* w3         = (const float*)d_in[16];
    const float* b3         = (const float*)d_in[17];
    const float* w5         = (const float*)d_in[18];
    const float* b5         = (const float*)d_in[19];
    const float* w4         = (const float*)d_in[20];
    const float* b4         = (const float*)d_in[21];

    unsigned char* emb8 = (unsigned char*)d_ws;   // 30000*256 = 7.68 MB
    float* out = (float*)d_out;

    normalize_kernel<<<NVOCAB / 4, 256, 0, stream>>>(emb, emb8);

    fused_kernel<<<BB, NT, 0, stream>>>(
        text_left, text_right, loc_left, distance, emb, attn_w,
        w_m0, b_m0, w_m1, b_m1, w_m2, b_m2, out_w, out_b,
        lat_tab, lon_tab, w3, b3, w5, b5, w4, b4, emb8, out);
}

// Round 5
// 89.273 us; speedup vs baseline: 5.9261x; 1.0928x over previous
//
#include <hip/hip_runtime.h>
#include <hip/hip_fp16.h>
#include <math.h>

#define BB 512
#define LL 10
#define RR 2048
#define DD 256
#define KK 20
#define HH 128
#define NVOCAB 30000
#define GEOD 64

#define NT 1024
#define RP 2052

#define FP8_SCALE   64.0f
#define FP8_DESCALE (1.0f / 4096.0f)

// workspace layout (bytes)
#define EMB8_BYTES (NVOCAB * DD)            // 7,680,000 (16-aligned)
#define BLOB1_OFF  EMB8_BYTES               // u16[4096]  = 8192 B
#define BLOB2_OFF  (BLOB1_OFF + 8192)       // u16[16384] = 32768 B
#define W3T_OFF    (BLOB2_OFF + 32768)      // f32[2560]  = 10240 B
#define W5T_OFF    (W3T_OFF + 10240)        // f32[2048]  = 8192 B

typedef __attribute__((ext_vector_type(2))) long long llx2;
typedef __attribute__((ext_vector_type(4))) float f32x4;
typedef __attribute__((ext_vector_type(8))) short bf16x8;

static __device__ inline unsigned short f2bf(float f) {
    unsigned u = __float_as_uint(f);
    unsigned r = (u + 0x7fff + ((u >> 16) & 1)) >> 16;   // RNE
    return (unsigned short)r;
}

// ---------------- Kernel A: normalized fp8 table in FRAGMENT-PERMUTED order ----
// permuted byte position p = q*64 + kk*8 + t  <-  original element e = kk*32 + q*8 + t
__global__ __launch_bounds__(256) void normalize_kernel(
    const float* __restrict__ emb, unsigned char* __restrict__ emb8)
{
    int row  = blockIdx.x * 4 + (threadIdx.x >> 6);
    int lane = threadIdx.x & 63;
    // this lane writes permuted bytes lane*4 .. +3  -> orig elements e0..e0+3
    int e0 = ((lane >> 1) & 7) * 32 + (lane >> 4) * 8 + (lane & 1) * 4;
    float4 v = *(const float4*)(emb + (size_t)row * DD + e0);
    float ssq = v.x * v.x + v.y * v.y + v.z * v.z + v.w * v.w;
    #pragma unroll
    for (int off = 32; off; off >>= 1) ssq += __shfl_xor(ssq, off);
    float s = FP8_SCALE / fmaxf(sqrtf(ssq), 1e-12f);
    unsigned pk = 0;
    pk = (unsigned)__builtin_amdgcn_cvt_pk_fp8_f32(v.x * s, v.y * s, (int)pk, false);
    pk = (unsigned)__builtin_amdgcn_cvt_pk_fp8_f32(v.z * s, v.w * s, (int)pk, true);
    ((unsigned*)(emb8 + (size_t)row * DD))[lane] = pk;
}

// ---------------- Kernel P: weight blobs (fragment-order bf16) + transposes ----
__global__ __launch_bounds__(256) void prep_kernel(
    const float* __restrict__ w_m0, const float* __restrict__ w_m1,
    const float* __restrict__ w3,   const float* __restrict__ w5,
    unsigned short* __restrict__ blob1, unsigned short* __restrict__ blob2,
    float* __restrict__ w3T, float* __restrict__ w5T)
{
    int i = blockIdx.x * 256 + threadIdx.x;
    if (i < 4096) {                       // layer-1 B fragments: [t][lane][8]
        int t = i >> 9, ln = (i >> 3) & 63, tt = i & 7;
        int n = t * 16 + (ln & 15), k = (ln >> 4) * 8 + tt;
        blob1[i] = (k < KK) ? f2bf(w_m0[k * HH + n]) : (unsigned short)0;
    } else if (i < 4096 + 16384) {        // layer-2 B fragments: [ks][t][lane][8]
        int i2 = i - 4096;
        int ks = i2 >> 12, rem = i2 & 4095;
        int t = rem >> 9, ln = (rem >> 3) & 63, tt = rem & 7;
        int n = t * 16 + (ln & 15), k = ks * 32 + (ln >> 4) * 8 + tt;
        blob2[i2] = f2bf(w_m1[k * HH + n]);
    } else if (i < 4096 + 16384 + 2560) { // w3T[10][256]
        int i3 = i - (4096 + 16384);
        int j = i3 >> 8, d = i3 & 255;
        w3T[i3] = w3[d * 10 + j];
    } else if (i < 4096 + 16384 + 2560 + 2048) { // w5T[32][64]
        int i4 = i - (4096 + 16384 + 2560);
        int c = i4 >> 6, d = i4 & 63;
        w5T[i4] = w5[d * 32 + c];
    }
}

static __device__ inline unsigned wave_umax_u32(unsigned x)
{
    unsigned t;
    t = (unsigned)__builtin_amdgcn_update_dpp((int)x, (int)x, 0x111, 0xF, 0xF, false); x = x > t ? x : t;
    t = (unsigned)__builtin_amdgcn_update_dpp((int)x, (int)x, 0x112, 0xF, 0xF, false); x = x > t ? x : t;
    t = (unsigned)__builtin_amdgcn_update_dpp((int)x, (int)x, 0x114, 0xF, 0xF, false); x = x > t ? x : t;
    t = (unsigned)__builtin_amdgcn_update_dpp((int)x, (int)x, 0x118, 0xF, 0xF, false); x = x > t ? x : t;
    t = (unsigned)__builtin_amdgcn_update_dpp((int)x, (int)x, 0x142, 0xF, 0xF, false); x = x > t ? x : t;
    t = (unsigned)__builtin_amdgcn_update_dpp((int)x, (int)x, 0x143, 0xF, 0xF, false); x = x > t ? x : t;
    return (unsigned)__builtin_amdgcn_readlane((int)x, 63);
}

static __device__ inline void build_top2(const unsigned short* __restrict__ row,
                                         int lane, unsigned extmask,
                                         unsigned& k1, unsigned& k2)
{
    unsigned m1 = 0u, m2 = 0u;
    #pragma unroll
    for (int k = 0; k < 32; ++k) {
        int j = lane + 64 * k;
        unsigned key = ((unsigned)row[j] << 16) | (unsigned)(2047 - j);
        key = ((extmask >> k) & 1u) ? 0u : key;
        bool gt = key > m1;
        unsigned nm2 = (key > m2) ? key : m2;
        m2 = gt ? m1 : nm2;
        m1 = gt ? key : m1;
    }
    k1 = m1; k2 = m2;
}

// ---------------- Kernel B: fused per-batch pipeline ----------------
__global__ __launch_bounds__(NT, 2) void fused_kernel(
    const int*   __restrict__ text_left,
    const int*   __restrict__ text_right,
    const int*   __restrict__ loc_left,
    const float* __restrict__ distance,
    const float* __restrict__ emb,
    const float* __restrict__ attn_w,
    const float* __restrict__ b_m0, const float* __restrict__ b_m1,
    const float* __restrict__ w_m2, const float* __restrict__ b_m2,
    const float* __restrict__ out_w, const float* __restrict__ out_b,
    const float* __restrict__ lat_tab, const float* __restrict__ lon_tab,
    const float* __restrict__ b3, const float* __restrict__ b5,
    const float* __restrict__ w4, const float* __restrict__ b4,
    const unsigned char*  __restrict__ emb8,   // permuted fp8 table
    const unsigned short* __restrict__ blob1,
    const unsigned short* __restrict__ blob2,
    const float* __restrict__ w3T, const float* __restrict__ w5T,
    float*       __restrict__ out)
{
    __shared__ __align__(16) unsigned char  s_stage[8 * 8192];   // 64 KB (8 waves x dbuf 4KB)
    __shared__ __align__(16) unsigned short s_keys[LL][RP];      // ~41 KB
    __shared__ int   s_docs[RR];                                 // 8 KB
    __shared__ __align__(16) unsigned char  s_qa[16 * 256];      // 4 KB (swizzled, permuted)
    __shared__ __align__(16) unsigned short s_h1[16 * 128];      // 4 KB bf16 (swizzled)
    __shared__ __align__(16) float s_topk[16][32];               // 2 KB (zero-padded)
    __shared__ float s_logit[LL];
    __shared__ float s_h[16];
    __shared__ float s_feat[164];

    const int b    = blockIdx.x;
    const int tid  = threadIdx.x;
    const int lane = tid & 63;
    const int wid  = tid >> 6;

    // ================= phase A: stage doc ids + fp8 q rows ==================
    {
        const int* trb = text_right + b * RR;
        #pragma unroll
        for (int t = tid; t < RR; t += NT) s_docs[t] = trb[t];
        // q rows: LDS[r][c'] = permuted chunk (c' ^ r) of query row r (zero for r>=LL)
        int r = tid >> 6, cp = (tid >> 2) & 15, sub = tid & 3;
        unsigned val = 0u;
        if (r < LL) {
            int v = text_left[b * LL + r];
            val = *(const unsigned*)(emb8 + (size_t)v * DD + ((cp ^ r) << 4) + (sub << 2));
        }
        *(unsigned*)(s_qa + r * 256 + (cp << 4) + (sub << 2)) = val;
        if (tid < 512) ((float*)s_topk)[tid] = 0.f;
    }
    __syncthreads();

    // ============ phase B: GEMM (waves 0-7)  ||  logits+geo (waves 8-11) ====
    if (wid < 8) {
        const int m15 = lane & 15, q = lane >> 4;
        llx2 afr[4];
        #pragma unroll
        for (int s = 0; s < 4; ++s)
            afr[s] = *(const llx2*)(s_qa + m15 * 256 + (((q * 4 + s) ^ m15) << 4));

        unsigned char* stg = s_stage + wid * 8192;
        const int r0 = lane >> 4;          // row sub-index: r = 4j + r0
        const int c15 = lane & 15;

        auto STAGE = [&](int i, int half) {
            int base = (wid * 16 + i) * 16;
            #pragma unroll
            for (int j = 0; j < 4; ++j) {
                int r = j * 4 + r0;
                int doc = s_docs[base + r];
                const unsigned char* g = emb8 + (size_t)doc * DD + ((c15 ^ r) << 4);
                __builtin_amdgcn_global_load_lds(
                    (const __attribute__((address_space(1))) void*)g,
                    (__attribute__((address_space(3))) void*)(stg + half * 4096 + j * 1024),
                    16, 0, 0);
            }
        };

        STAGE(0, 0);
        #pragma unroll 1
        for (int i = 0; i < 16; ++i) {
            int half = i & 1;
            if (i < 15) {
                STAGE(i + 1, half ^ 1);
                asm volatile("s_waitcnt vmcnt(4)" ::: "memory");
            } else {
                asm volatile("s_waitcnt vmcnt(0)" ::: "memory");
            }
            __builtin_amdgcn_sched_barrier(0);
            const unsigned char* hb = stg + half * 4096;
            f32x4 acc = {0.f, 0.f, 0.f, 0.f};
            #pragma unroll
            for (int s = 0; s < 4; ++s) {
                llx2 bf = *(const llx2*)(hb + m15 * 256 + (((q * 4 + s) ^ m15) << 4));
                acc = __builtin_amdgcn_mfma_f32_16x16x32_fp8_fp8(afr[s][0], bf[0], acc, 0, 0, 0);
                acc = __builtin_amdgcn_mfma_f32_16x16x32_fp8_fp8(afr[s][1], bf[1], acc, 0, 0, 0);
            }
            int n0 = (wid * 16 + i) * 16;
            #pragma unroll
            for (int v = 0; v < 4; ++v) {
                int m = q * 4 + v;
                if (m < LL) {
                    float sc = acc[v] * FP8_DESCALE;
                    unsigned hbits = (unsigned)__half_as_ushort(__float2half(sc));
                    unsigned okey = hbits ^ ((hbits & 0x8000u) ? 0xFFFFu : 0x8000u);
                    s_keys[m][n0 + m15] = (unsigned short)okey;
                }
            }
        }
    } else if (wid == 8) {
        // attention logits
        const float4 aw = *(const float4*)(attn_w + lane * 4);
        for (int l = 0; l < LL; ++l) {
            int v = text_left[b * LL + l];
            float4 qv = *(const float4*)(emb + (size_t)v * DD + lane * 4);
            float d = qv.x * aw.x + qv.y * aw.y + qv.z * aw.z + qv.w * aw.w;
            #pragma unroll
            for (int off = 32; off; off >>= 1) d += __shfl_xor(d, off);
            if (lane == 0) s_logit[l] = (v == 0) ? -INFINITY : d;
        }
    } else if (wid == 9 || wid == 10) {
        int p = (wid - 9) * 64 + lane;
        if (p < 100) {
            int l = p / 10, j = p % 10;
            int v = text_left[b * LL + l];
            const float4* qr = (const float4*)(emb + (size_t)v * DD);
            const float4* wr = (const float4*)(w3T + j * DD);
            float a = b3[j];
            #pragma unroll 8
            for (int d4 = 0; d4 < 64; ++d4) {
                float4 qv = qr[d4], wv = wr[d4];
                a += qv.x * wv.x + qv.y * wv.y + qv.z * wv.z + qv.w * wv.w;
            }
            s_feat[p] = a;
        }
    } else if (wid == 11) {
        int c = lane & 31, which = lane >> 5;
        int v = loc_left[b * 2 + which];
        const float* tab = which ? lon_tab : lat_tab;
        const float4* tr = (const float4*)(tab + (size_t)v * GEOD);
        const float4* wr = (const float4*)(w5T + c * GEOD);
        float a = b5[c];
        #pragma unroll
        for (int d4 = 0; d4 < 16; ++d4) {
            float4 tv = tr[d4], wv = wr[d4];
            a += tv.x * wv.x + tv.y * wv.y + tv.z * wv.z + tv.w * wv.w;
        }
        s_feat[100 + which * 32 + c] = a;
    }
    __syncthreads();

    // ================= phase C: top-20 per row (waves 0-9) ==================
    if (wid < LL) {
        const int l = wid;
        const unsigned short* krow = &s_keys[l][0];
        unsigned extmask = 0u, k1, k2;
        build_top2(krow, lane, extmask, k1, k2);
        #pragma unroll 1
        for (int it = 0; it < KK; ++it) {
            unsigned bmk = wave_umax_u32(k1);
            if (k1 == bmk) {
                unsigned o16 = bmk >> 16;
                unsigned hbv = (o16 & 0x8000u) ? (o16 & 0x7FFFu) : (o16 ^ 0xFFFFu);
                s_topk[l][it] = __half2float(__ushort_as_half((unsigned short)hbv));
                int j = 2047 - (int)(bmk & 0xFFFFu);
                extmask |= 1u << (j >> 6);
                k1 = k2; k2 = 0u;
            }
            if (__any(k1 == 0u)) {
                if (k1 == 0u) build_top2(krow, lane, extmask, k1, k2);
            }
        }
    }
    __syncthreads();

    // ================= phase D: MFMA MLP + softmax + output (wave 0) ========
    if (wid == 0) {
        const int m15 = lane & 15, q = lane >> 4;
        // ---- layer 1: topk[16x32] @ w_m0 -> h1[16x128] ----
        float tv[8];
        *(float4*)(tv)     = *(const float4*)(&s_topk[m15][q * 8]);
        *(float4*)(tv + 4) = *(const float4*)(&s_topk[m15][q * 8 + 4]);
        bf16x8 a1;
        #pragma unroll
        for (int t = 0; t < 8; ++t) a1[t] = (short)f2bf(tv[t]);
        f32x4 acc1[8];
        #pragma unroll
        for (int t = 0; t < 8; ++t) {
            bf16x8 b1 = *(const bf16x8*)(blob1 + t * 512 + lane * 8);
            f32x4 z = {0.f, 0.f, 0.f, 0.f};
            acc1[t] = __builtin_amdgcn_mfma_f32_16x16x32_bf16(a1, b1, z, 0, 0, 0);
        }
        #pragma unroll
        for (int t = 0; t < 8; ++t) {
            int c = t * 16 + m15;
            float bb0 = b_m0[c];
            #pragma unroll
            for (int v = 0; v < 4; ++v) {
                int m = q * 4 + v;
                float h = tanhf(acc1[t][v] + bb0);
                s_h1[m * 128 + (((c >> 3) ^ m) << 3) + (c & 7)] = f2bf(h);
            }
        }
        // ---- layer 2: h1[16x128] @ w_m1 -> h2[16x128] (fragments from LDS) --
        f32x4 acc2[8];
        #pragma unroll
        for (int t = 0; t < 8; ++t) acc2[t] = (f32x4){0.f, 0.f, 0.f, 0.f};
        #pragma unroll
        for (int ks = 0; ks < 4; ++ks) {
            bf16x8 a2 = *(const bf16x8*)(s_h1 + m15 * 128 + (((ks * 4 + q) ^ m15) << 3));
            #pragma unroll
            for (int t = 0; t < 8; ++t) {
                bf16x8 b2 = *(const bf16x8*)(blob2 + (ks * 8 + t) * 512 + lane * 8);
                acc2[t] = __builtin_amdgcn_mfma_f32_16x16x32_bf16(a2, b2, acc2[t], 0, 0, 0);
            }
        }
        // ---- layer 3 + reduce ----
        float part[4] = {0.f, 0.f, 0.f, 0.f};
        #pragma unroll
        for (int t = 0; t < 8; ++t) {
            int c = t * 16 + m15;
            float bb1 = b_m1[c];
            float wm2 = w_m2[c];
            #pragma unroll
            for (int v = 0; v < 4; ++v)
                part[v] += tanhf(acc2[t][v] + bb1) * wm2;
        }
        #pragma unroll
        for (int v = 0; v < 4; ++v) {
            #pragma unroll
            for (int off = 1; off < 16; off <<= 1) part[v] += __shfl_xor(part[v], off);
        }
        if (m15 == 0) {
            #pragma unroll
            for (int v = 0; v < 4; ++v) {
                int m = q * 4 + v;
                if (m < LL) s_h[m] = tanhf(part[v] + b_m2[0]);
            }
        }
        // ---- softmax + frozen x + final output (lane 0) ----
        if (lane == 0) {
            float mx = -INFINITY;
            #pragma unroll
            for (int l = 0; l < LL; ++l) mx = fmaxf(mx, s_logit[l]);
            float ex[LL];
            float sum = 0.f;
            #pragma unroll
            for (int l = 0; l < LL; ++l) { ex[l] = expf(s_logit[l] - mx); sum += ex[l]; }
            float x = 0.f;
            #pragma unroll
            for (int l = 0; l < LL; ++l) x += s_h[l] * (ex[l] / sum);
            float xo = tanhf(x * out_w[0] + out_b[0]);

            float w0 = b4[0], w1 = b4[1];
            for (int i = 0; i < 164; ++i) {
                w0 += s_feat[i] * w4[i * 2 + 0];
                w1 += s_feat[i] * w4[i * 2 + 1];
            }
            out[b] = w0 * xo + w1 * distance[b];
        }
    }
}

extern "C" void kernel_launch(void* const* d_in, const int* in_sizes, int n_in,
                              void* d_out, int out_size, void* d_ws, size_t ws_size,
                              hipStream_t stream) {
    const int*   text_left  = (const int*)  d_in[0];
    const int*   text_right = (const int*)  d_in[1];
    const int*   loc_left   = (const int*)  d_in[2];
    const float* distance   = (const float*)d_in[3];
    const float* emb        = (const float*)d_in[4];
    const float* attn_w     = (const float*)d_in[5];
    const float* w_m0       = (const float*)d_in[6];
    const float* b_m0       = (const float*)d_in[7];
    const float* w_m1       = (const float*)d_in[8];
    const float* b_m1       = (const float*)d_in[9];
    const float* w_m2       = (const float*)d_in[10];
    const float* b_m2       = (const float*)d_in[11];
    const float* out_w      = (const float*)d_in[12];
    const float* out_b      = (const float*)d_in[13];
    const float* lat_tab    = (const float*)d_in[14];
    const float* lon_tab    = (const float*)d_in[15];
    const float* w3         = (const float*)d_in[16];
    const float* b3         = (const float*)d_in[17];
    const float* w5         = (const float*)d_in[18];
    const float* b5         = (const float*)d_in[19];
    const float* w4         = (const float*)d_in[20];
    const float* b4         = (const float*)d_in[21];

    unsigned char*  ws    = (unsigned char*)d_ws;
    unsigned char*  emb8  = ws;
    unsigned short* blob1 = (unsigned short*)(ws + BLOB1_OFF);
    unsigned short* blob2 = (unsigned short*)(ws + BLOB2_OFF);
    float*          w3T   = (float*)(ws + W3T_OFF);
    float*          w5T   = (float*)(ws + W5T_OFF);
    float*          out   = (float*)d_out;

    normalize_kernel<<<NVOCAB / 4, 256, 0, stream>>>(emb, emb8);
    prep_kernel<<<98, 256, 0, stream>>>(w_m0, w_m1, w3, w5, blob1, blob2, w3T, w5T);

    fused_kernel<<<BB, NT, 0, stream>>>(
        text_left, text_right, loc_left, distance, emb, attn_w,
        b_m0, b_m1, w_m2, b_m2, out_w, out_b,
        lat_tab, lon_tab, b3, b5, w4, b4,
        emb8, blob1, blob2, w3T, w5T, out);
}

// Round 6
// 72.350 us; speedup vs baseline: 7.3122x; 1.2339x over previous
//
#include <hip/hip_runtime.h>
#include <hip/hip_fp16.h>
#include <math.h>

#define BB 512
#define LL 10
#define RR 2048
#define DD 256
#define KK 20
#define HH 128
#define NVOCAB 30000
#define GEOD 64

#define NT 512

#define FP8_SCALE   64.0f
#define FP8_DESCALE (1.0f / 4096.0f)

// workspace layout (bytes)
#define EMB8_BYTES (NVOCAB * DD)            // 7,680,000
#define BLOB1_OFF  EMB8_BYTES               // u16[4096]  = 8192 B
#define BLOB2_OFF  (BLOB1_OFF + 8192)       // u16[16384] = 32768 B
#define W3T_OFF    (BLOB2_OFF + 32768)      // f32[2560]  = 10240 B
#define W5T_OFF    (W3T_OFF + 10240)        // f32[2048]  = 8192 B

typedef __attribute__((ext_vector_type(2))) long long llx2;
typedef __attribute__((ext_vector_type(4))) float f32x4;
typedef __attribute__((ext_vector_type(8))) short bf16x8;

static __device__ inline unsigned short f2bf(float f) {
    unsigned u = __float_as_uint(f);
    unsigned r = (u + 0x7fff + ((u >> 16) & 1)) >> 16;   // RNE
    return (unsigned short)r;
}

// ---------------- Kernel PRE: normalize (permuted fp8) + weight prep --------
// blocks 0..7499: normalize; blocks 7500..7597: prep (25088 items)
__global__ __launch_bounds__(256) void pre_kernel(
    const float* __restrict__ emb,
    const float* __restrict__ w_m0, const float* __restrict__ w_m1,
    const float* __restrict__ w3,   const float* __restrict__ w5,
    unsigned char* __restrict__ emb8,
    unsigned short* __restrict__ blob1, unsigned short* __restrict__ blob2,
    float* __restrict__ w3T, float* __restrict__ w5T)
{
    if (blockIdx.x < 7500) {
        int row  = blockIdx.x * 4 + (threadIdx.x >> 6);
        int lane = threadIdx.x & 63;
        // permuted byte p = q*64 + kk*8 + t  <-  element e = kk*32 + q*8 + t
        int e0 = ((lane >> 1) & 7) * 32 + (lane >> 4) * 8 + (lane & 1) * 4;
        float4 v = *(const float4*)(emb + (size_t)row * DD + e0);
        float ssq = v.x * v.x + v.y * v.y + v.z * v.z + v.w * v.w;
        #pragma unroll
        for (int off = 32; off; off >>= 1) ssq += __shfl_xor(ssq, off);
        float s = FP8_SCALE / fmaxf(sqrtf(ssq), 1e-12f);
        unsigned pk = 0;
        pk = (unsigned)__builtin_amdgcn_cvt_pk_fp8_f32(v.x * s, v.y * s, (int)pk, false);
        pk = (unsigned)__builtin_amdgcn_cvt_pk_fp8_f32(v.z * s, v.w * s, (int)pk, true);
        ((unsigned*)(emb8 + (size_t)row * DD))[lane] = pk;
    } else {
        int i = (blockIdx.x - 7500) * 256 + threadIdx.x;
        if (i < 4096) {                       // layer-1 B fragments: [t][lane][8]
            int t = i >> 9, ln = (i >> 3) & 63, tt = i & 7;
            int n = t * 16 + (ln & 15), k = (ln >> 4) * 8 + tt;
            blob1[i] = (k < KK) ? f2bf(w_m0[k * HH + n]) : (unsigned short)0;
        } else if (i < 4096 + 16384) {        // layer-2 B fragments: [ks][t][lane][8]
            int i2 = i - 4096;
            int ks = i2 >> 12, rem = i2 & 4095;
            int t = rem >> 9, ln = (rem >> 3) & 63, tt = rem & 7;
            int n = t * 16 + (ln & 15), k = ks * 32 + (ln >> 4) * 8 + tt;
            blob2[i2] = f2bf(w_m1[k * HH + n]);
        } else if (i < 4096 + 16384 + 2560) { // w3T[10][256]
            int i3 = i - (4096 + 16384);
            int j = i3 >> 8, d = i3 & 255;
            w3T[i3] = w3[d * 10 + j];
        } else if (i < 4096 + 16384 + 2560 + 2048) { // w5T[32][64]
            int i4 = i - (4096 + 16384 + 2560);
            int c = i4 >> 6, d = i4 & 63;
            w5T[i4] = w5[d * 32 + c];
        }
    }
}

static __device__ inline unsigned wave_umax_u32(unsigned x)
{
    unsigned t;
    t = (unsigned)__builtin_amdgcn_update_dpp((int)x, (int)x, 0x111, 0xF, 0xF, false); x = x > t ? x : t;
    t = (unsigned)__builtin_amdgcn_update_dpp((int)x, (int)x, 0x112, 0xF, 0xF, false); x = x > t ? x : t;
    t = (unsigned)__builtin_amdgcn_update_dpp((int)x, (int)x, 0x114, 0xF, 0xF, false); x = x > t ? x : t;
    t = (unsigned)__builtin_amdgcn_update_dpp((int)x, (int)x, 0x118, 0xF, 0xF, false); x = x > t ? x : t;
    t = (unsigned)__builtin_amdgcn_update_dpp((int)x, (int)x, 0x142, 0xF, 0xF, false); x = x > t ? x : t;
    t = (unsigned)__builtin_amdgcn_update_dpp((int)x, (int)x, 0x143, 0xF, 0xF, false); x = x > t ? x : t;
    return (unsigned)__builtin_amdgcn_readlane((int)x, 63);
}

static __device__ inline void build_top2(const unsigned short* __restrict__ row,
                                         int lane, unsigned extmask,
                                         unsigned& k1, unsigned& k2)
{
    unsigned m1 = 0u, m2 = 0u;
    #pragma unroll
    for (int k = 0; k < 32; ++k) {
        int j = lane + 64 * k;
        unsigned key = ((unsigned)row[j] << 16) | (unsigned)(2047 - j);
        key = ((extmask >> k) & 1u) ? 0u : key;
        bool gt = key > m1;
        unsigned nm2 = (key > m2) ? key : m2;
        m2 = gt ? m1 : nm2;
        m1 = gt ? key : m1;
    }
    k1 = m1; k2 = m2;
}

// ---------------- Kernel B: fused per-batch pipeline ----------------
__global__ __launch_bounds__(NT, 4) void fused_kernel(
    const int*   __restrict__ text_left,
    const int*   __restrict__ text_right,
    const int*   __restrict__ loc_left,
    const float* __restrict__ distance,
    const float* __restrict__ emb,
    const float* __restrict__ attn_w,
    const float* __restrict__ b_m0, const float* __restrict__ b_m1,
    const float* __restrict__ w_m2, const float* __restrict__ b_m2,
    const float* __restrict__ out_w, const float* __restrict__ out_b,
    const float* __restrict__ lat_tab, const float* __restrict__ lon_tab,
    const float* __restrict__ b3, const float* __restrict__ b5,
    const float* __restrict__ w4, const float* __restrict__ b4,
    const unsigned char*  __restrict__ emb8,   // permuted fp8 table
    const unsigned short* __restrict__ blob1,
    const unsigned short* __restrict__ blob2,
    const float* __restrict__ w3T, const float* __restrict__ w5T,
    float*       __restrict__ out)
{
    __shared__ __align__(16) unsigned short s_keys[LL][RR];   // 40 KB
    __shared__ __align__(16) unsigned short s_h1[16 * 128];   // 4 KB bf16 (swizzled)
    __shared__ __align__(16) float s_topk[16][32];            // 2 KB (zero-padded)
    __shared__ float s_logit[LL];
    __shared__ float s_h[16];
    __shared__ float s_feat[164];

    const int b    = blockIdx.x;
    const int tid  = threadIdx.x;
    const int lane = tid & 63;
    const int wid  = tid >> 6;
    const int m15  = lane & 15, q = lane >> 4;

    ((float*)s_topk)[tid] = 0.f;   // 512 == 16*32

    // ============ phase B: register-dbuf fp8 GEMM, all 8 waves ==============
    {
        // A fragments: query row m15 (row 0 is all-zero -> pads m>=10)
        llx2 afr[4];
        {
            int qidx = (m15 < LL) ? text_left[b * LL + m15] : 0;
            const unsigned char* ap = emb8 + (size_t)qidx * DD + q * 64;
            #pragma unroll
            for (int s = 0; s < 4; ++s) afr[s] = *(const llx2*)(ap + s * 16);
        }
        const int* trb = text_right + b * RR;

        auto LOADB = [&](int T, llx2* buf) {
            int doc = trb[T * 16 + m15];
            const unsigned char* bp = emb8 + (size_t)doc * DD + q * 64;
            #pragma unroll
            for (int s = 0; s < 4; ++s) buf[s] = *(const llx2*)(bp + s * 16);
        };
        auto COMPUTE = [&](int T, const llx2* buf) {
            f32x4 acc = {0.f, 0.f, 0.f, 0.f};
            #pragma unroll
            for (int s = 0; s < 4; ++s) {
                acc = __builtin_amdgcn_mfma_f32_16x16x32_fp8_fp8(afr[s][0], buf[s][0], acc, 0, 0, 0);
                acc = __builtin_amdgcn_mfma_f32_16x16x32_fp8_fp8(afr[s][1], buf[s][1], acc, 0, 0, 0);
            }
            int n0 = T * 16;
            #pragma unroll
            for (int v = 0; v < 4; ++v) {
                int m = q * 4 + v;
                if (m < LL) {
                    float sc = acc[v] * FP8_DESCALE;
                    unsigned hbits = (unsigned)__half_as_ushort(__float2half(sc));
                    unsigned okey = hbits ^ ((hbits & 0x8000u) ? 0xFFFFu : 0x8000u);
                    s_keys[m][n0 + m15] = (unsigned short)okey;
                }
            }
        };

        llx2 bufA[4], bufB[4];
        const int T0 = wid * 16;
        LOADB(T0, bufA);
        #pragma unroll 1
        for (int i = 0; i < 16; i += 2) {
            LOADB(T0 + i + 1, bufB);
            COMPUTE(T0 + i, bufA);
            if (i < 14) LOADB(T0 + i + 2, bufA);
            COMPUTE(T0 + i + 1, bufB);
        }
    }
    __syncthreads();

    // ====== phase C: top-k (all waves) + feats/logits on waves 2-5 ==========
    {
        auto TOPK_ROW = [&](int l) {
            const unsigned short* krow = &s_keys[l][0];
            unsigned extmask = 0u, k1, k2;
            build_top2(krow, lane, extmask, k1, k2);
            #pragma unroll 1
            for (int it = 0; it < KK; ++it) {
                unsigned bmk = wave_umax_u32(k1);
                if (k1 == bmk) {
                    unsigned o16 = bmk >> 16;
                    unsigned hbv = (o16 & 0x8000u) ? (o16 & 0x7FFFu) : (o16 ^ 0xFFFFu);
                    s_topk[l][it] = __half2float(__ushort_as_half((unsigned short)hbv));
                    int j = 2047 - (int)(bmk & 0xFFFFu);
                    extmask |= 1u << (j >> 6);
                    k1 = k2; k2 = 0u;
                }
                if (__any(k1 == 0u)) {
                    if (k1 == 0u) build_top2(krow, lane, extmask, k1, k2);
                }
            }
        };
        TOPK_ROW(wid);                       // rows 0..7
        if (wid >= 6) {
            TOPK_ROW(wid + 2);               // rows 8,9
        } else if (wid == 4) {
            // attention logits
            const float4 aw = *(const float4*)(attn_w + lane * 4);
            for (int l = 0; l < LL; ++l) {
                int v = text_left[b * LL + l];
                float4 qv = *(const float4*)(emb + (size_t)v * DD + lane * 4);
                float d = qv.x * aw.x + qv.y * aw.y + qv.z * aw.z + qv.w * aw.w;
                #pragma unroll
                for (int off = 32; off; off >>= 1) d += __shfl_xor(d, off);
                if (lane == 0) s_logit[l] = (v == 0) ? -INFINITY : d;
            }
        } else if (wid == 5) {
            // geo features
            int c = lane & 31, which = lane >> 5;
            int v = loc_left[b * 2 + which];
            const float* tab = which ? lon_tab : lat_tab;
            const float4* tr = (const float4*)(tab + (size_t)v * GEOD);
            const float4* wr = (const float4*)(w5T + c * GEOD);
            float a = b5[c];
            #pragma unroll
            for (int d4 = 0; d4 < 16; ++d4) {
                float4 tv = tr[d4], wv = wr[d4];
                a += tv.x * wv.x + tv.y * wv.y + tv.z * wv.z + tv.w * wv.w;
            }
            s_feat[100 + which * 32 + c] = a;
        } else if (wid == 2 || wid == 3) {
            // q1 projection features
            int p = (wid - 2) * 64 + lane;
            if (p < 100) {
                int l = p / 10, j = p % 10;
                int v = text_left[b * LL + l];
                const float4* qr = (const float4*)(emb + (size_t)v * DD);
                const float4* wr = (const float4*)(w3T + j * DD);
                float a = b3[j];
                #pragma unroll 8
                for (int d4 = 0; d4 < 64; ++d4) {
                    float4 qv = qr[d4], wv = wr[d4];
                    a += qv.x * wv.x + qv.y * wv.y + qv.z * wv.z + qv.w * wv.w;
                }
                s_feat[p] = a;
            }
        }
    }
    __syncthreads();

    // ================= phase D: MFMA MLP + softmax + output (wave 0) ========
    if (wid == 0) {
        // ---- layer 1: topk[16x32] @ w_m0 -> h1[16x128] ----
        float tv[8];
        *(float4*)(tv)     = *(const float4*)(&s_topk[m15][q * 8]);
        *(float4*)(tv + 4) = *(const float4*)(&s_topk[m15][q * 8 + 4]);
        bf16x8 a1;
        #pragma unroll
        for (int t = 0; t < 8; ++t) a1[t] = (short)f2bf(tv[t]);
        f32x4 acc1[8];
        #pragma unroll
        for (int t = 0; t < 8; ++t) {
            bf16x8 b1 = *(const bf16x8*)(blob1 + t * 512 + lane * 8);
            f32x4 z = {0.f, 0.f, 0.f, 0.f};
            acc1[t] = __builtin_amdgcn_mfma_f32_16x16x32_bf16(a1, b1, z, 0, 0, 0);
        }
        #pragma unroll
        for (int t = 0; t < 8; ++t) {
            int c = t * 16 + m15;
            float bb0 = b_m0[c];
            #pragma unroll
            for (int v = 0; v < 4; ++v) {
                int m = q * 4 + v;
                float h = tanhf(acc1[t][v] + bb0);
                s_h1[m * 128 + (((c >> 3) ^ m) << 3) + (c & 7)] = f2bf(h);
            }
        }
        // ---- layer 2 ----
        f32x4 acc2[8];
        #pragma unroll
        for (int t = 0; t < 8; ++t) acc2[t] = (f32x4){0.f, 0.f, 0.f, 0.f};
        #pragma unroll
        for (int ks = 0; ks < 4; ++ks) {
            bf16x8 a2 = *(const bf16x8*)(s_h1 + m15 * 128 + (((ks * 4 + q) ^ m15) << 3));
            #pragma unroll
            for (int t = 0; t < 8; ++t) {
                bf16x8 b2 = *(const bf16x8*)(blob2 + (ks * 8 + t) * 512 + lane * 8);
                acc2[t] = __builtin_amdgcn_mfma_f32_16x16x32_bf16(a2, b2, acc2[t], 0, 0, 0);
            }
        }
        // ---- layer 3 + reduce ----
        float part[4] = {0.f, 0.f, 0.f, 0.f};
        #pragma unroll
        for (int t = 0; t < 8; ++t) {
            int c = t * 16 + m15;
            float bb1 = b_m1[c];
            float wm2 = w_m2[c];
            #pragma unroll
            for (int v = 0; v < 4; ++v)
                part[v] += tanhf(acc2[t][v] + bb1) * wm2;
        }
        #pragma unroll
        for (int v = 0; v < 4; ++v) {
            #pragma unroll
            for (int off = 1; off < 16; off <<= 1) part[v] += __shfl_xor(part[v], off);
        }
        if (m15 == 0) {
            #pragma unroll
            for (int v = 0; v < 4; ++v) {
                int m = q * 4 + v;
                if (m < LL) s_h[m] = tanhf(part[v] + b_m2[0]);
            }
        }
        // ---- softmax + frozen x + final output (lane 0) ----
        if (lane == 0) {
            float mx = -INFINITY;
            #pragma unroll
            for (int l = 0; l < LL; ++l) mx = fmaxf(mx, s_logit[l]);
            float ex[LL];
            float sum = 0.f;
            #pragma unroll
            for (int l = 0; l < LL; ++l) { ex[l] = expf(s_logit[l] - mx); sum += ex[l]; }
            float x = 0.f;
            #pragma unroll
            for (int l = 0; l < LL; ++l) x += s_h[l] * (ex[l] / sum);
            float xo = tanhf(x * out_w[0] + out_b[0]);

            float w0 = b4[0], w1 = b4[1];
            for (int i = 0; i < 164; ++i) {
                w0 += s_feat[i] * w4[i * 2 + 0];
                w1 += s_feat[i] * w4[i * 2 + 1];
            }
            out[b] = w0 * xo + w1 * distance[b];
        }
    }
}

extern "C" void kernel_launch(void* const* d_in, const int* in_sizes, int n_in,
                              void* d_out, int out_size, void* d_ws, size_t ws_size,
                              hipStream_t stream) {
    const int*   text_left  = (const int*)  d_in[0];
    const int*   text_right = (const int*)  d_in[1];
    const int*   loc_left   = (const int*)  d_in[2];
    const float* distance   = (const float*)d_in[3];
    const float* emb        = (const float*)d_in[4];
    const float* attn_w     = (const float*)d_in[5];
    const float* w_m0       = (const float*)d_in[6];
    const float* b_m0       = (const float*)d_in[7];
    const float* w_m1       = (const float*)d_in[8];
    const float* b_m1       = (const float*)d_in[9];
    const float* w_m2       = (const float*)d_in[10];
    const float* b_m2       = (const float*)d_in[11];
    const float* out_w      = (const float*)d_in[12];
    const float* out_b      = (const float*)d_in[13];
    const float* lat_tab    = (const float*)d_in[14];
    const float* lon_tab    = (const float*)d_in[15];
    const float* w3         = (const float*)d_in[16];
    const float* b3         = (const float*)d_in[17];
    const float* w5         = (const float*)d_in[18];
    const float* b5         = (const float*)d_in[19];
    const float* w4         = (const float*)d_in[20];
    const float* b4         = (const float*)d_in[21];

    unsigned char*  ws    = (unsigned char*)d_ws;
    unsigned char*  emb8  = ws;
    unsigned short* blob1 = (unsigned short*)(ws + BLOB1_OFF);
    unsigned short* blob2 = (unsigned short*)(ws + BLOB2_OFF);
    float*          w3T   = (float*)(ws + W3T_OFF);
    float*          w5T   = (float*)(ws + W5T_OFF);
    float*          out   = (float*)d_out;

    pre_kernel<<<7598, 256, 0, stream>>>(emb, w_m0, w_m1, w3, w5,
                                         emb8, blob1, blob2, w3T, w5T);

    fused_kernel<<<BB, NT, 0, stream>>>(
        text_left, text_right, loc_left, distance, emb, attn_w,
        b_m0, b_m1, w_m2, b_m2, out_w, out_b,
        lat_tab, lon_tab, b3, b5, w4, b4,
        emb8, blob1, blob2, w3T, w5T, out);
}